// Round 9
// baseline (279.279 us; speedup 1.0000x reference)
//
#include <hip/hip_runtime.h>

// 3D neighborhood attention (KS=3) + softmax + expected-offset contraction.
// q,k: (1,64,64,64,96) fp32 ; rpb: (6,3,3,3) fp32 ; out: (1,18,64,64,64) fp32
//
// Round 5 -> 6 (structure kept: quad-split channels + TS=4 t-strip):
//  * explicit 2-column register double-buffer: ISSUE(c+1) loads are in flight
//    while COMPUTE(c) runs; round 5 stalled each column on its own 6 loads
//    (VALUBusy 40%, occupancy 17%), pure latency loss.
//  * transpose-reduce butterfly: instead of full quad-reduce of all 12 dots +
//    keep-own-via-cndmask (60 VALU/col), a 2-round select+DPP butterfly lands
//    dot[u=s] directly in lane s (36 VALU/col).
//  * macros take LITERAL column ids -> every array index compile-time (the
//    round-2/3 spill bug class); launch_bounds(384,4) caps VGPR at 128.
//  Gate: WRITE_SIZE must stay ~19 MB (spill tell).
// (Rounds 6/7/8 benches were GPU-acquisition timeouts; same kernel resubmitted.)

#define DH 64
#define DW 64
#define DT 64
#define DC 96
#define NH 6
#define HD 16

__device__ __forceinline__ float dpp_xor1(float x) {
    return __int_as_float(__builtin_amdgcn_mov_dpp(__float_as_int(x), 0xB1, 0xF, 0xF, true));
}
__device__ __forceinline__ float dpp_xor2(float x) {
    return __int_as_float(__builtin_amdgcn_mov_dpp(__float_as_int(x), 0x4E, 0xF, 0xF, true));
}

__global__ __launch_bounds__(384, 4) void natten3d_kernel(
    const float* __restrict__ q,
    const float* __restrict__ k,
    const float* __restrict__ rpb,
    float* __restrict__ out)
{
    // 4096 blocks (one per (h,w)), bijective XCD swizzle: 512 contiguous/XCD
    int bid = blockIdx.x;
    int nb  = (bid & 7) * 512 + (bid >> 3);
    int h = nb >> 6;
    int w = nb & 63;

    int tid  = threadIdx.x;
    int s    = tid & 3;          // quad lane: channel slice AND owned output
    int r    = tid >> 2;         // 0..95
    int n    = r % NH;           // head (fast -> dense wave addresses)
    int t0   = (r / NH) * 4;     // strip base; quad covers t0..t0+3
    int tout = t0 + s;           // output position this lane owns

    const bool m1 = (s & 1) != 0;
    const bool m2 = (s & 2) != 0;
    const bool dok0 = (tout >= 1);        // dt=-1 in range
    const bool dok2 = (tout <= DT - 2);   // dt=+1 in range

    // ---- q fragments (lane holds channels 4s..4s+3 of 4 outputs), pre-scaled
    float4 qv[4];
    {
        const float* qp = q + ((size_t)((h * DW + w) * DT + t0)) * DC + n * HD + s * 4;
        #pragma unroll
        for (int u = 0; u < 4; ++u) {
            float4 v = *reinterpret_cast<const float4*>(qp + u * DC);
            v.x *= 0.25f; v.y *= 0.25f; v.z *= 0.25f; v.w *= 0.25f;  // hd^-0.5
            qv[u] = v;
        }
    }

    // ---- block-uniform neighbor-column offsets (clamped) + validity (SGPRs)
    int  coff[9];
    bool cok[9];
    #pragma unroll
    for (int c = 0; c < 9; ++c) {
        int di = c / 3, dj = c % 3;
        int hh = h + di - 1, ww = w + dj - 1;
        cok[c] = ((unsigned)hh < DH) && ((unsigned)ww < DW);
        int hc = min(max(hh, 0), DH - 1);
        int wc = min(max(ww, 0), DW - 1);
        coff[c] = (hc * DW + wc) * DT * DC;
    }

    // ---- per-lane slice offsets, j=0..5 <-> tt = t0+j-1 (clamped)
    int soff[6];
    #pragma unroll
    for (int j = 0; j < 6; ++j) {
        int tt = min(max(t0 + j - 1, 0), DT - 1);
        soff[j] = tt * DC + n * HD + s * 4;
    }

    float acc_l = 0.f, acc0 = 0.f, acc1 = 0.f, acc2 = 0.f;
    const int rbase = n * 27;

    float4 kbA[6], kbB[6];
    float  rbA[3], rbB[3];

// NOTE: c is always a LITERAL -> all indices compile-time (no scratch).
#define ISSUE(c, kb, rb) do {                                                  \
    const float* kc_ = k + (size_t)coff[c];                                    \
    _Pragma("unroll")                                                          \
    for (int j = 0; j < 6; ++j)                                                \
        kb[j] = *reinterpret_cast<const float4*>(kc_ + soff[j]);               \
    rb[0] = rpb[rbase + (c) * 3 + 0];                                          \
    rb[1] = rpb[rbase + (c) * 3 + 1];                                          \
    rb[2] = rpb[rbase + (c) * 3 + 2];                                          \
} while (0)

#define COMPUTE(c, kb, rb) do {                                                \
    _Pragma("unroll")                                                          \
    for (int d = 0; d < 3; ++d) {                                              \
        /* 4-ch partials of the 4 outputs' dots for this dt */                 \
        float p0_ = kb[d+0].x*qv[0].x; p0_ = fmaf(qv[0].y,kb[d+0].y,p0_);      \
        p0_ = fmaf(qv[0].z,kb[d+0].z,p0_); p0_ = fmaf(qv[0].w,kb[d+0].w,p0_);  \
        float p1_ = kb[d+1].x*qv[1].x; p1_ = fmaf(qv[1].y,kb[d+1].y,p1_);      \
        p1_ = fmaf(qv[1].z,kb[d+1].z,p1_); p1_ = fmaf(qv[1].w,kb[d+1].w,p1_);  \
        float p2_ = kb[d+2].x*qv[2].x; p2_ = fmaf(qv[2].y,kb[d+2].y,p2_);      \
        p2_ = fmaf(qv[2].z,kb[d+2].z,p2_); p2_ = fmaf(qv[2].w,kb[d+2].w,p2_);  \
        float p3_ = kb[d+3].x*qv[3].x; p3_ = fmaf(qv[3].y,kb[d+3].y,p3_);      \
        p3_ = fmaf(qv[3].z,kb[d+3].z,p3_); p3_ = fmaf(qv[3].w,kb[d+3].w,p3_);  \
        /* transpose-reduce: lane s ends with full dot of output u=s */        \
        float u1_ = m1 ? p1_ : p0_;                                            \
        float v1_ = m1 ? p0_ : p1_;                                            \
        u1_ += dpp_xor1(v1_);                                                  \
        float w1_ = m1 ? p3_ : p2_;                                            \
        float x1_ = m1 ? p2_ : p3_;                                            \
        w1_ += dpp_xor1(x1_);                                                  \
        float u2_ = m2 ? w1_ : u1_;                                            \
        float v2_ = m2 ? u1_ : w1_;                                            \
        float dot_ = u2_ + dpp_xor2(v2_);                                      \
        bool valid_ = cok[c] && (d == 0 ? dok0 : (d == 2 ? dok2 : true));      \
        float logit_ = (valid_ ? dot_ : 0.f) + rb[d];  /* zero-pad semantics */\
        float pe_ = __expf(logit_);            /* logits ~N(0,1): no max pass */\
        acc_l += pe_;                                                          \
        if ((c)/3 == 0) acc0 -= pe_; else if ((c)/3 == 2) acc0 += pe_;         \
        if ((c)%3 == 0) acc1 -= pe_; else if ((c)%3 == 2) acc1 += pe_;         \
        if (d == 0)     acc2 -= pe_; else if (d == 2)     acc2 += pe_;         \
    }                                                                          \
} while (0)

    // ---- software pipeline over the 9 columns (depth 2, register dbuf)
    ISSUE(0, kbA, rbA);
    ISSUE(1, kbB, rbB);
    COMPUTE(0, kbA, rbA); ISSUE(2, kbA, rbA);
    COMPUTE(1, kbB, rbB); ISSUE(3, kbB, rbB);
    COMPUTE(2, kbA, rbA); ISSUE(4, kbA, rbA);
    COMPUTE(3, kbB, rbB); ISSUE(5, kbB, rbB);
    COMPUTE(4, kbA, rbA); ISSUE(6, kbA, rbA);
    COMPUTE(5, kbB, rbB); ISSUE(7, kbB, rbB);
    COMPUTE(6, kbA, rbA); ISSUE(8, kbA, rbA);
    COMPUTE(7, kbB, rbB);
    COMPUTE(8, kbA, rbA);

#undef ISSUE
#undef COMPUTE

    // ---- normalize + write: each lane writes its own output position
    float inv = 1.f / acc_l;
    size_t plane = (size_t)DH * DW * DT;
    size_t sp = (size_t)((h * DW + w) * DT) + tout;
    out[(size_t)(n * 3 + 0) * plane + sp] = acc0 * inv;
    out[(size_t)(n * 3 + 1) * plane + sp] = acc1 * inv;
    out[(size_t)(n * 3 + 2) * plane + sp] = acc2 * inv;
}

extern "C" void kernel_launch(void* const* d_in, const int* in_sizes, int n_in,
                              void* d_out, int out_size, void* d_ws, size_t ws_size,
                              hipStream_t stream) {
    const float* q   = (const float*)d_in[0];
    const float* k   = (const float*)d_in[1];
    const float* rpb = (const float*)d_in[2];
    float* out = (float*)d_out;

    dim3 grid(DH * DW);       // 4096 blocks: one (h,w) column each
    dim3 block(16 * NH * 4);  // 384 threads = 16 strips x 6 heads x 4 lanes
    hipLaunchKernelGGL(natten3d_kernel, grid, block, 0, stream, q, k, rpb, out);
}

// Round 11
// 262.302 us; speedup vs baseline: 1.0647x; 1.0647x over previous
//
#include <hip/hip_runtime.h>

// 3D neighborhood attention (KS=3) + softmax + expected-offset contraction.
// q,k: (1,64,64,64,96) fp32 ; rpb: (6,3,3,3) fp32 ; out: (1,18,64,64,64) fp32
//
// Round 9 -> 10: TLP instead of ILP. Round-9's register double-buffer was
// defeated by the allocator (VGPR 64: loads sunk to uses, prefetch dead);
// ~70% of time is unhidden latency with only ~1.5-2 resident waves/SIMD.
// Changes:
//  * 192-thread blocks (3 waves) -> finer wave-packing on 4 SIMDs; block
//    covers (h, w, t-half of 32). Grid 8192 (%8==0, bijective XCD swizzle;
//    both t-halves of one (h,w) land on the same XCD for L2 column reuse).
//  * single kb[6] buffer, plain unrolled column loop (compiler schedules
//    waits; resident-wave TLP hides latency instead of in-wave prefetch).
//  * keep quad-split + TS=4 t-strip + transpose-reduce butterfly (29% VALU).
//  Gate: WRITE_SIZE ~19 MB (spill tell), VGPR <= 64.
// (Round 10 bench was a GPU-acquisition timeout; same kernel resubmitted.)

#define DH 64
#define DW 64
#define DT 64
#define DC 96
#define NH 6
#define HD 16

__device__ __forceinline__ float dpp_xor1(float x) {
    return __int_as_float(__builtin_amdgcn_mov_dpp(__float_as_int(x), 0xB1, 0xF, 0xF, true));
}
__device__ __forceinline__ float dpp_xor2(float x) {
    return __int_as_float(__builtin_amdgcn_mov_dpp(__float_as_int(x), 0x4E, 0xF, 0xF, true));
}

__global__ __launch_bounds__(192) void natten3d_kernel(
    const float* __restrict__ q,
    const float* __restrict__ k,
    const float* __restrict__ rpb,
    float* __restrict__ out)
{
    // 8192 blocks, bijective XCD swizzle: 1024 contiguous per XCD
    int bid = blockIdx.x;
    int nb  = (bid & 7) * 1024 + (bid >> 3);
    int thalf = nb & 1;          // t-half fastest: same (h,w) pair on same XCD
    int w     = (nb >> 1) & 63;
    int h     = nb >> 7;

    int tid   = threadIdx.x;
    int s     = tid & 3;         // quad lane: channel slice AND owned output
    int r     = tid >> 2;        // 0..47
    int n     = r % NH;          // head (fast -> dense wave addresses)
    int strip = r / NH;          // 0..7
    int t0    = thalf * 32 + strip * 4;
    int tout  = t0 + s;          // output position this lane owns

    const bool m1 = (s & 1) != 0;
    const bool m2 = (s & 2) != 0;
    const bool dok0 = (tout >= 1);
    const bool dok2 = (tout <= DT - 2);

    // ---- q fragments (lane holds channels 4s..4s+3 of 4 outputs), pre-scaled
    float4 qv[4];
    {
        const float* qp = q + ((size_t)((h * DW + w) * DT + t0)) * DC + n * HD + s * 4;
        #pragma unroll
        for (int u = 0; u < 4; ++u) {
            float4 v = *reinterpret_cast<const float4*>(qp + u * DC);
            v.x *= 0.25f; v.y *= 0.25f; v.z *= 0.25f; v.w *= 0.25f;  // hd^-0.5
            qv[u] = v;
        }
    }

    // ---- block-uniform neighbor-column offsets (clamped) + validity (SGPRs)
    int  coff[9];
    bool cok[9];
    #pragma unroll
    for (int c = 0; c < 9; ++c) {
        int di = c / 3, dj = c % 3;
        int hh = h + di - 1, ww = w + dj - 1;
        cok[c] = ((unsigned)hh < DH) && ((unsigned)ww < DW);
        int hc = min(max(hh, 0), DH - 1);
        int wc = min(max(ww, 0), DW - 1);
        coff[c] = (hc * DW + wc) * DT * DC;
    }

    // ---- per-lane slice offsets, j=0..5 <-> tt = t0+j-1 (clamped)
    int soff[6];
    #pragma unroll
    for (int j = 0; j < 6; ++j) {
        int tt = min(max(t0 + j - 1, 0), DT - 1);
        soff[j] = tt * DC + n * HD + s * 4;
    }

    float acc_l = 0.f, acc0 = 0.f, acc1 = 0.f, acc2 = 0.f;
    const int rbase = n * 27;

    #pragma unroll
    for (int c = 0; c < 9; ++c) {          // fully unrolled: c compile-time
        // 6 dense k-slices for this column (each: contiguous wave-dense read)
        float4 kb[6];
        #pragma unroll
        for (int j = 0; j < 6; ++j)
            kb[j] = *reinterpret_cast<const float4*>(k + (size_t)(coff[c] + soff[j]));

        float rb0 = rpb[rbase + c * 3 + 0];
        float rb1 = rpb[rbase + c * 3 + 1];
        float rb2 = rpb[rbase + c * 3 + 2];

        #pragma unroll
        for (int d = 0; d < 3; ++d) {
            // 4-ch partials of the 4 outputs' dots for this dt
            float p0 = kb[d+0].x * qv[0].x; p0 = fmaf(qv[0].y, kb[d+0].y, p0);
            p0 = fmaf(qv[0].z, kb[d+0].z, p0); p0 = fmaf(qv[0].w, kb[d+0].w, p0);
            float p1 = kb[d+1].x * qv[1].x; p1 = fmaf(qv[1].y, kb[d+1].y, p1);
            p1 = fmaf(qv[1].z, kb[d+1].z, p1); p1 = fmaf(qv[1].w, kb[d+1].w, p1);
            float p2 = kb[d+2].x * qv[2].x; p2 = fmaf(qv[2].y, kb[d+2].y, p2);
            p2 = fmaf(qv[2].z, kb[d+2].z, p2); p2 = fmaf(qv[2].w, kb[d+2].w, p2);
            float p3 = kb[d+3].x * qv[3].x; p3 = fmaf(qv[3].y, kb[d+3].y, p3);
            p3 = fmaf(qv[3].z, kb[d+3].z, p3); p3 = fmaf(qv[3].w, kb[d+3].w, p3);

            // transpose-reduce: lane s ends with full 16-ch dot of output u=s
            float u1 = m1 ? p1 : p0;
            float v1 = m1 ? p0 : p1;
            u1 += dpp_xor1(v1);
            float w1 = m1 ? p3 : p2;
            float x1 = m1 ? p2 : p3;
            w1 += dpp_xor1(x1);
            float u2 = m2 ? w1 : u1;
            float v2 = m2 ? u1 : w1;
            float dot = u2 + dpp_xor2(v2);

            bool valid = cok[c] && (d == 0 ? dok0 : (d == 2 ? dok2 : true));
            float rb = (d == 0) ? rb0 : (d == 1) ? rb1 : rb2;
            float logit = (valid ? dot : 0.f) + rb;   // zero-pad semantics
            float pe = __expf(logit);                 // logits ~N(0,1): no max pass
            acc_l += pe;
            if (c / 3 == 0) acc0 -= pe; else if (c / 3 == 2) acc0 += pe;
            if (c % 3 == 0) acc1 -= pe; else if (c % 3 == 2) acc1 += pe;
            if (d == 0)     acc2 -= pe; else if (d == 2)     acc2 += pe;
        }
    }

    // ---- normalize + write: each lane writes its own output position
    float inv = 1.f / acc_l;
    size_t plane = (size_t)DH * DW * DT;
    size_t sp = (size_t)((h * DW + w) * DT) + tout;
    out[(size_t)(n * 3 + 0) * plane + sp] = acc0 * inv;
    out[(size_t)(n * 3 + 1) * plane + sp] = acc1 * inv;
    out[(size_t)(n * 3 + 2) * plane + sp] = acc2 * inv;
}

extern "C" void kernel_launch(void* const* d_in, const int* in_sizes, int n_in,
                              void* d_out, int out_size, void* d_ws, size_t ws_size,
                              hipStream_t stream) {
    const float* q   = (const float*)d_in[0];
    const float* k   = (const float*)d_in[1];
    const float* rpb = (const float*)d_in[2];
    float* out = (float*)d_out;

    dim3 grid(DH * DW * 2);   // 8192 blocks: (h, w, t-half)
    dim3 block(8 * NH * 4);   // 192 threads = 8 strips x 6 heads x 4 lanes
    hipLaunchKernelGGL(natten3d_kernel, grid, block, 0, stream, q, k, rpb, out);
}